// Round 12
// baseline (107.454 us; speedup 1.0000x reference)
//
#include <hip/hip_runtime.h>
#include <hip/hip_bf16.h>
#include <cstdint>

// LSTM cell, B=16384, IN=512, H=512, fused 4-gate bf16 MFMA GEMM.
// Round 12: A operand bypasses LDS entirely (global->VGPR asm loads, 2 reg
// sets, counted vmcnt); only B is DMA-staged (3-deep 16KB ring, 48KB LDS).
// Rationale: r6 probe + r11 control showed staging's 32KB/tile adds ~1460cy
// serially on the LDS/TCP port; cutting LDS-pipe bytes 130KB->49KB per tile.

typedef __attribute__((ext_vector_type(8))) __bf16 bf16x8;
typedef __attribute__((ext_vector_type(4))) float f32x4;
typedef __attribute__((address_space(3))) char lds_char;

#define GLOAD_LDS16(gp, lp)                                                        \
    __builtin_amdgcn_global_load_lds(                                              \
        (const __attribute__((address_space(1))) void*)(gp),                       \
        (__attribute__((address_space(3))) void*)(lp), 16, 0, 0)

#define BAR()   asm volatile("s_barrier" ::: "memory")
#define VMW10() asm volatile("s_waitcnt vmcnt(10)" ::: "memory")
#define VMW8()  asm volatile("s_waitcnt vmcnt(8)" ::: "memory")
#define VMW0()  asm volatile("s_waitcnt vmcnt(0)" ::: "memory")
#define LGK0() { asm volatile("s_waitcnt lgkmcnt(0)" ::: "memory");                \
                 __builtin_amdgcn_sched_barrier(0); }
#define DSR(dst, off)                                                              \
    asm volatile("ds_read_b128 %0, %1" : "=v"(dst) : "v"(lds3 + (off)))
#define GLD(dst, addr, OFF)                                                        \
    asm volatile("global_load_dwordx4 %0, %1, off offset:" #OFF                    \
                 : "=v"(dst) : "v"(addr))

__device__ __forceinline__ unsigned short f2bf(float f) {
    unsigned int u = __float_as_uint(f);
    u = (u + 0x7FFFu + ((u >> 16) & 1u)) >> 16;   // RNE
    return (unsigned short)u;
}
__device__ __forceinline__ float tanh_fast(float x) {
    float ax = fabsf(x);
    float e  = __expf(2.f * ax);
    float t  = 1.f - 2.f / (e + 1.f);
    return copysignf(t, x);
}

// ---------------- prepass A: lane-linear, NO swizzle ----------------
// A_pre: [mt=64][t=32] 16KB slices; chunk p (0..1023, 16B):
//   m16 = p>>6, kc = (p>>4)&3, r16 = p&15
//   data = bf16(combined[mt*256 + m16*16 + r16][t*32 + kc*8 .. +8])
// GEMM wave read: byte = m16*1024 + lane*16 (fully lane-linear, coalesced).
__global__ __launch_bounds__(256) void conv_a_kernel(const float* __restrict__ x,
                                                     const float* __restrict__ h,
                                                     unsigned short* __restrict__ A) {
    int G   = blockIdx.x * 256 + threadIdx.x;   // 2,097,152 chunks
    int b   = G >> 10;                           // mt*32 + t
    int p   = G & 1023;
    int mt  = b >> 5;
    int t   = b & 31;
    int m16 = p >> 6;
    int kc  = (p >> 4) & 3;
    int r16 = p & 15;
    int r   = mt * 256 + m16 * 16 + r16;
    int k0  = t * 32 + kc * 8;
    const float* src = (k0 < 512) ? (x + (size_t)r * 512 + k0)
                                  : (h + (size_t)r * 512 + (k0 - 512));
    const float4* s4 = reinterpret_cast<const float4*>(src);
    float4 v0 = s4[0];
    float4 v1 = s4[1];
    uint4 o;
    o.x = (unsigned)f2bf(v0.x) | ((unsigned)f2bf(v0.y) << 16);
    o.y = (unsigned)f2bf(v0.z) | ((unsigned)f2bf(v0.w) << 16);
    o.z = (unsigned)f2bf(v1.x) | ((unsigned)f2bf(v1.y) << 16);
    o.w = (unsigned)f2bf(v1.z) | ((unsigned)f2bf(v1.w) << 16);
    *reinterpret_cast<uint4*>(A + ((size_t)b * 1024 + p) * 8) = o;
}

// ---------------- prepass B (r5, verified, unchanged) ----------------
__global__ __launch_bounds__(256) void conv_w_kernel(const float* __restrict__ w0,
                                                     const float* __restrict__ w1,
                                                     const float* __restrict__ w2,
                                                     const float* __restrict__ w3,
                                                     unsigned short* __restrict__ Wt) {
    int G  = blockIdx.x * 256 + threadIdx.x;
    int b  = G >> 10;
    int p  = G & 1023;
    int nb = b >> 5;
    int kt = (b >> 1) & 15;
    int ks = b & 1;
    int col = p >> 2;
    int c   = (p & 3) ^ ((col >> 1) & 3);
    int g   = col >> 6;
    int hh  = col & 63;
    int n   = nb * 64 + hh;
    int k0  = kt * 64 + ks * 32 + c * 8;
    const float* Wg = (g == 0) ? w0 : (g == 1) ? w1 : (g == 2) ? w2 : w3;
    unsigned short us[8];
    #pragma unroll
    for (int u = 0; u < 8; ++u) us[u] = f2bf(Wg[(size_t)(k0 + u) * 512 + n]);
    uint4 o;
    o.x = (unsigned)us[0] | ((unsigned)us[1] << 16);
    o.y = (unsigned)us[2] | ((unsigned)us[3] << 16);
    o.z = (unsigned)us[4] | ((unsigned)us[5] << 16);
    o.w = (unsigned)us[6] | ((unsigned)us[7] << 16);
    *reinterpret_cast<uint4*>(Wt + ((size_t)b * 1024 + p) * 8) = o;
}

// ---------------- fused GEMM: A direct-to-reg, B-only LDS ring ----------------
__global__ __launch_bounds__(512, 2) void lstm_gemm8(
    const char* __restrict__ Apre, const char* __restrict__ Bpre,
    const float* __restrict__ c_cur,
    const float* __restrict__ bi_p, const float* __restrict__ bf_p,
    const float* __restrict__ bo_p, const float* __restrict__ bc_p,
    float* __restrict__ h_out, float* __restrict__ c_out)
{
    extern __shared__ char smem[];
    lds_char* lds3 = (lds_char*)smem;
    const int tid  = threadIdx.x;
    const int lane = tid & 63;
    const int wid  = tid >> 6;
    const int wm   = wid >> 2;    // 0..1
    const int wn   = wid & 3;     // 0..3

    // XCD-grouped mapping (r11, FETCH-verified)
    const int mt = (blockIdx.x & 7) * 8 + (blockIdx.x >> 6);
    const int nb = (blockIdx.x >> 3) & 7;

    const int ar    = lane & 15;
    const int swz   = ((lane >> 4) ^ ((ar >> 1) & 3)) << 4;
    const int boffb = (wn * 16 + ar) * 64 + swz;
    const int swl   = wid * 1024;

    const char* ApreT = Apre + (((size_t)mt * 32) << 14)
                             + (size_t)wm * 8192 + (size_t)lane * 16;
    const char* BpreB = Bpre + (((size_t)nb * 32) << 14) + (size_t)tid * 16;

#define STAGE_B(t, bb) {                                                \
        const char* gb_ = BpreB + (((size_t)(t)) << 14);                \
        GLOAD_LDS16(gb_,        smem + (bb) + swl);                     \
        GLOAD_LDS16(gb_ + 8192, smem + (bb) + 8192 + swl); }
#define ALOADS(t, SET) {                                                \
        const char* a0_ = ApreT + (((size_t)(t)) << 14);                \
        const char* a1_ = a0_ + 4096;                                   \
        GLD(SET[0], a0_, 0);                                            \
        GLD(SET[1], a0_, 1024);                                         \
        GLD(SET[2], a0_, 2048);                                         \
        GLD(SET[3], a0_, 3072);                                         \
        GLD(SET[4], a1_, 0);                                            \
        GLD(SET[5], a1_, 1024);                                         \
        GLD(SET[6], a1_, 2048);                                         \
        GLD(SET[7], a1_, 3072); }

    f32x4 acc[4][8];
    #pragma unroll
    for (int g = 0; g < 4; ++g)
        #pragma unroll
        for (int m = 0; m < 8; ++m)
            acc[g][m] = (f32x4){0.f, 0.f, 0.f, 0.f};

    bf16x8 aA[8], aB[8], bFr[4];

#define MMALL(SET)                                                      \
    _Pragma("unroll")                                                   \
    for (int g = 0; g < 4; ++g)                                         \
        _Pragma("unroll")                                               \
        for (int m = 0; m < 8; ++m)                                     \
            acc[g][m] = __builtin_amdgcn_mfma_f32_16x16x32_bf16(        \
                SET[m], bFr[g], acc[g][m], 0, 0, 0);

// Per sub-iter J: stage B(J+2) DMA, read B(J) frags, issue A(J+1) into NXT,
// wait A(J) in CUR (vmcnt = younger ops: 2 DMA + 8 loads = 10), MFMA, BAR.
#define SUBITER(J, CUR, NXT) {                                          \
        const int buf_ = ((J) % 3) * 16384;                             \
        if ((J) + 2 < 32) STAGE_B((J) + 2, (((J) + 2) % 3) * 16384);    \
        __builtin_amdgcn_sched_barrier(0);                              \
        DSR(bFr[0], buf_ + boffb);                                      \
        DSR(bFr[1], buf_ + 4096 + boffb);                               \
        DSR(bFr[2], buf_ + 8192 + boffb);                               \
        DSR(bFr[3], buf_ + 12288 + boffb);                              \
        if ((J) + 1 < 32) ALOADS((J) + 1, NXT);                         \
        __builtin_amdgcn_sched_barrier(0);                              \
        if ((J) <= 29)      { VMW10(); }                                \
        else if ((J) == 30) { VMW8(); }                                 \
        else                { VMW0(); }                                 \
        LGK0();                                                         \
        __builtin_amdgcn_s_setprio(1);                                  \
        MMALL(CUR);                                                     \
        __builtin_amdgcn_s_setprio(0);                                  \
        BAR(); }

    // prologue: B(0)->buf0, B(1)->buf1 (DMA), A(0)->aA; drain; sync.
    STAGE_B(0, 0);
    STAGE_B(1, 16384);
    ALOADS(0, aA);
    VMW0();
    BAR();

    #pragma unroll 1
    for (int i = 0; i < 16; ++i) {
        const int j0 = 2 * i;
        SUBITER(j0,     aA, aB);
        SUBITER(j0 + 1, aB, aA);
    }

    // fused LSTM epilogue (verified): all 4 gates in-lane
    const int r4   = (lane >> 4) * 4;
    const int hcol = nb * 64 + wn * 16 + ar;
    const float bii = bi_p[hcol], bff = bf_p[hcol];
    const float boo = bo_p[hcol], bcc = bc_p[hcol];
    #pragma unroll
    for (int m = 0; m < 8; ++m) {
        const int rowb = mt * 256 + wm * 128 + m * 16 + r4;
        #pragma unroll
        for (int rr = 0; rr < 4; ++rr) {
            const size_t o = (size_t)(rowb + rr) * 512 + hcol;
            float gi = acc[0][m][rr] + bii;
            float gf = acc[1][m][rr] + bff;
            float go = acc[2][m][rr] + boo;
            float gc = acc[3][m][rr] + bcc;
            float is = 1.f / (1.f + __expf(-gi));
            float fs = 1.f / (1.f + __expf(-gf));
            float os = 1.f / (1.f + __expf(-go));
            float ct = tanh_fast(gc);
            float cn = fs * c_cur[o] + is * ct;
            h_out[o] = os * tanh_fast(cn);
            c_out[o] = cn;
        }
    }
#undef STAGE_B
#undef ALOADS
#undef MMALL
#undef SUBITER
}

extern "C" void kernel_launch(void* const* d_in, const int* in_sizes, int n_in,
                              void* d_out, int out_size, void* d_ws, size_t ws_size,
                              hipStream_t stream) {
    const float* x   = (const float*)d_in[0];
    const float* h   = (const float*)d_in[1];
    const float* c   = (const float*)d_in[2];
    const float* W_i = (const float*)d_in[3];
    const float* b_i = (const float*)d_in[4];
    const float* W_f = (const float*)d_in[5];
    const float* b_f = (const float*)d_in[6];
    const float* W_o = (const float*)d_in[7];
    const float* b_o = (const float*)d_in[8];
    const float* W_c = (const float*)d_in[9];
    const float* b_c = (const float*)d_in[10];

    unsigned short* Apre = (unsigned short*)d_ws;
    unsigned short* Bpre = (unsigned short*)((char*)d_ws + 33554432);

    float* h_out = (float*)d_out;
    float* c_out = h_out + (size_t)16384 * 512;

    (void)hipFuncSetAttribute(reinterpret_cast<const void*>(lstm_gemm8),
                              hipFuncAttributeMaxDynamicSharedMemorySize, 49152);

    conv_a_kernel<<<8192, 256, 0, stream>>>(x, h, Apre);
    conv_w_kernel<<<1024, 256, 0, stream>>>(W_i, W_f, W_o, W_c, Bpre);
    lstm_gemm8<<<512, 512, 49152, stream>>>((const char*)Apre, (const char*)Bpre,
                                            c, b_i, b_f, b_o, b_c, h_out, c_out);
}

// Round 13
// 97.627 us; speedup vs baseline: 1.1007x; 1.1007x over previous
//
#include <hip/hip_runtime.h>
#include <hip/hip_bf16.h>
#include <cstdint>

// LSTM cell, B=16384, IN=512, H=512, fused 4-gate bf16 MFMA GEMM.
// Round 13: r7 geometry (256x128 tile, 2 blocks/CU, 16 waves/CU — the only
// lever that moved the GEMM: co-resident blocks de-phase TCP/LDS/MFMA pipes)
// + r11's XCD-grouped mapping (kills r7's 281MB A-refetch; A panel L2-served).

typedef __attribute__((ext_vector_type(8))) __bf16 bf16x8;
typedef __attribute__((ext_vector_type(4))) float f32x4;
typedef __attribute__((address_space(3))) char lds_char;

#define GLOAD_LDS16(gp, lp)                                                        \
    __builtin_amdgcn_global_load_lds(                                              \
        (const __attribute__((address_space(1))) void*)(gp),                       \
        (__attribute__((address_space(3))) void*)(lp), 16, 0, 0)

#define BAR()  asm volatile("s_barrier" ::: "memory")
#define VMW3() asm volatile("s_waitcnt vmcnt(3)" ::: "memory")
#define VMW0() asm volatile("s_waitcnt vmcnt(0)" ::: "memory")
#define LGK0() { asm volatile("s_waitcnt lgkmcnt(0)" ::: "memory");                \
                 __builtin_amdgcn_sched_barrier(0); }
#define DSR(dst, off)                                                              \
    asm volatile("ds_read_b128 %0, %1" : "=v"(dst) : "v"(lds3 + (off)))

__device__ __forceinline__ unsigned short f2bf(float f) {
    unsigned int u = __float_as_uint(f);
    u = (u + 0x7FFFu + ((u >> 16) & 1u)) >> 16;   // RNE
    return (unsigned short)u;
}
__device__ __forceinline__ float tanh_fast(float x) {
    float ax = fabsf(x);
    float e  = __expf(2.f * ax);
    float t  = 1.f - 2.f / (e + 1.f);
    return copysignf(t, x);
}

// ---------------- prepass A (r5/r7, verified) ----------------
// A_pre: [mt=64][t=32] 16KB slices, slice t covers k[t*32, t*32+32).
__global__ __launch_bounds__(256) void conv_a_kernel(const float* __restrict__ x,
                                                     const float* __restrict__ h,
                                                     unsigned short* __restrict__ A) {
    int G  = blockIdx.x * 256 + threadIdx.x;
    int b  = G >> 10;
    int p  = G & 1023;
    int mt = b >> 5;
    int kt = (b >> 1) & 15;
    int ks = b & 1;
    int row = p >> 2;
    int c   = (p & 3) ^ ((row >> 1) & 3);
    int r   = mt * 256 + row;
    int k0  = kt * 64 + ks * 32 + c * 8;
    const float* src = (k0 < 512) ? (x + (size_t)r * 512 + k0)
                                  : (h + (size_t)r * 512 + (k0 - 512));
    const float4* s4 = reinterpret_cast<const float4*>(src);
    float4 v0 = s4[0];
    float4 v1 = s4[1];
    uint4 o;
    o.x = (unsigned)f2bf(v0.x) | ((unsigned)f2bf(v0.y) << 16);
    o.y = (unsigned)f2bf(v0.z) | ((unsigned)f2bf(v0.w) << 16);
    o.z = (unsigned)f2bf(v1.x) | ((unsigned)f2bf(v1.y) << 16);
    o.w = (unsigned)f2bf(v1.z) | ((unsigned)f2bf(v1.w) << 16);
    *reinterpret_cast<uint4*>(A + ((size_t)b * 1024 + p) * 8) = o;
}

// ---------------- prepass B (r7 layout, verified) ----------------
// B_pre: [nb=16][t=32] 8KB slices; chunk p: col=p>>2 (0..127) = g*32+h_local,
// kc=(p&3)^((col>>1)&3); n = nb*32+h_local; value = bf16(W_g[t*32+kc*8+u][n]).
__global__ __launch_bounds__(256) void conv_w_kernel(const float* __restrict__ w0,
                                                     const float* __restrict__ w1,
                                                     const float* __restrict__ w2,
                                                     const float* __restrict__ w3,
                                                     unsigned short* __restrict__ Wt) {
    int G  = blockIdx.x * 256 + threadIdx.x;   // 262,144 chunks
    int b  = G >> 9;    // 0..511
    int p  = G & 511;
    int nb = b >> 5;    // 0..15
    int t  = b & 31;
    int col = p >> 2;
    int kc  = (p & 3) ^ ((col >> 1) & 3);
    int g   = col >> 5;
    int n   = nb * 32 + (col & 31);
    int k0  = t * 32 + kc * 8;
    const float* Wg = (g == 0) ? w0 : (g == 1) ? w1 : (g == 2) ? w2 : w3;
    unsigned short us[8];
    #pragma unroll
    for (int u = 0; u < 8; ++u) us[u] = f2bf(Wg[(size_t)(k0 + u) * 512 + n]);
    uint4 o;
    o.x = (unsigned)us[0] | ((unsigned)us[1] << 16);
    o.y = (unsigned)us[2] | ((unsigned)us[3] << 16);
    o.z = (unsigned)us[4] | ((unsigned)us[5] << 16);
    o.w = (unsigned)us[6] | ((unsigned)us[7] << 16);
    *reinterpret_cast<uint4*>(Wt + ((size_t)b * 512 + p) * 8) = o;
}

// ---------------- fused GEMM: 256x128 tile, 2 blocks/CU, XCD-grouped ----------------
// LDS ring: 3 bufs x 24KB (A 16KB + B 8KB) = 72KB; 2 blocks/CU (144KB/160KB).
__global__ __launch_bounds__(512, 4) void lstm_gemm8(
    const char* __restrict__ Apre, const char* __restrict__ Bpre,
    const float* __restrict__ c_cur,
    const float* __restrict__ bi_p, const float* __restrict__ bf_p,
    const float* __restrict__ bo_p, const float* __restrict__ bc_p,
    float* __restrict__ h_out, float* __restrict__ c_out)
{
    extern __shared__ char smem[];
    lds_char* lds3 = (lds_char*)smem;
    const int tid  = threadIdx.x;
    const int lane = tid & 63;
    const int wid  = tid >> 6;    // 0..7
    const int wm   = wid >> 1;    // 0..3 (64-row group)
    const int wn   = wid & 1;     // 0..1 (16-h half)

    // XCD-grouped bijective mapping (THE round-13 change vs r7):
    // XCD k = bid&7 owns mt in {8k..8k+7}; for each mt its 16 nb-sharers are
    // adjacent dispatches on the same XCD -> A panel (0.5MB) L2-resident.
    const int mt = (blockIdx.x & 7) * 8 + (blockIdx.x >> 7);
    const int nb = (blockIdx.x >> 3) & 15;

    const int ar    = lane & 15;
    const int swz   = ((lane >> 4) ^ ((ar >> 1) & 3)) << 4;
    const int aoffb = ar * 64 + swz;
    const int boffb = 16384 + (wn * 16 + ar) * 64 + swz;
    const int swl   = wid * 1024;

    const char* ApreB = Apre + (((size_t)mt * 32) << 14) + (size_t)tid * 16;
    const char* BpreB = Bpre + (((size_t)nb * 32) << 13) + (size_t)tid * 16;

    // stage K-tile t into ring buffer bb: A 16KB (2 loads) + B 8KB (1 load)
#define STAGE(t, bb) {                                                  \
        const char* ga_ = ApreB + (((size_t)(t)) << 14);                \
        const char* gb_ = BpreB + (((size_t)(t)) << 13);                \
        GLOAD_LDS16(ga_,        smem + (bb) + swl);                     \
        GLOAD_LDS16(ga_ + 8192, smem + (bb) + 8192 + swl);              \
        GLOAD_LDS16(gb_,        smem + (bb) + 16384 + swl); }

    f32x4 acc[4][4];   // [gate][m-frag] = 64 regs
    #pragma unroll
    for (int g = 0; g < 4; ++g)
        #pragma unroll
        for (int m = 0; m < 4; ++m)
            acc[g][m] = (f32x4){0.f, 0.f, 0.f, 0.f};

    bf16x8 aFr[4], bFr[4];

    // prologue: stage K-tiles 0,1 into bufs 0,1 (6 loads in flight)
    STAGE(0, 0);
    STAGE(1, 24576);

    #pragma unroll 1
    for (int j = 0; j < 32; ++j) {
        const int buf  = (j % 3) * 24576;
        const int bufN = ((j + 2) % 3) * 24576;

        if (j < 31) { VMW3(); } else { VMW0(); }
        BAR();
        // stage j+2 into buf((j+2)%3) == buf(j-1): safe, all reads of j-1
        // retired before this barrier (lgkmcnt(0) preceded it in iter j-1).
        if (j < 30) STAGE(j + 2, bufN);

        #pragma unroll
        for (int mi = 0; mi < 4; ++mi)
            DSR(aFr[mi], buf + wm * 4096 + mi * 1024 + aoffb);
        #pragma unroll
        for (int g = 0; g < 4; ++g)
            DSR(bFr[g], buf + g * 2048 + boffb);

        LGK0();
        __builtin_amdgcn_s_setprio(1);
        #pragma unroll
        for (int g = 0; g < 4; ++g)
            #pragma unroll
            for (int m = 0; m < 4; ++m)
                acc[g][m] = __builtin_amdgcn_mfma_f32_16x16x32_bf16(
                    aFr[m], bFr[g], acc[g][m], 0, 0, 0);
        __builtin_amdgcn_s_setprio(0);
    }

    // fused LSTM epilogue (verified): all 4 gates in-lane
    const int r4   = (lane >> 4) * 4;
    const int hcol = nb * 32 + wn * 16 + ar;
    const float bii = bi_p[hcol], bff = bf_p[hcol];
    const float boo = bo_p[hcol], bcc = bc_p[hcol];
    #pragma unroll
    for (int m = 0; m < 4; ++m) {
        const int rowb = mt * 256 + wm * 64 + m * 16 + r4;
        #pragma unroll
        for (int rr = 0; rr < 4; ++rr) {
            const size_t o = (size_t)(rowb + rr) * 512 + hcol;
            float gi = acc[0][m][rr] + bii;
            float gf = acc[1][m][rr] + bff;
            float go = acc[2][m][rr] + boo;
            float gc = acc[3][m][rr] + bcc;
            float is = 1.f / (1.f + __expf(-gi));
            float fs = 1.f / (1.f + __expf(-gf));
            float os = 1.f / (1.f + __expf(-go));
            float ct = tanh_fast(gc);
            float cn = fs * c_cur[o] + is * ct;
            h_out[o] = os * tanh_fast(cn);
            c_out[o] = cn;
        }
    }
#undef STAGE
}

extern "C" void kernel_launch(void* const* d_in, const int* in_sizes, int n_in,
                              void* d_out, int out_size, void* d_ws, size_t ws_size,
                              hipStream_t stream) {
    const float* x   = (const float*)d_in[0];
    const float* h   = (const float*)d_in[1];
    const float* c   = (const float*)d_in[2];
    const float* W_i = (const float*)d_in[3];
    const float* b_i = (const float*)d_in[4];
    const float* W_f = (const float*)d_in[5];
    const float* b_f = (const float*)d_in[6];
    const float* W_o = (const float*)d_in[7];
    const float* b_o = (const float*)d_in[8];
    const float* W_c = (const float*)d_in[9];
    const float* b_c = (const float*)d_in[10];

    unsigned short* Apre = (unsigned short*)d_ws;                      // 33,554,432 B
    unsigned short* Bpre = (unsigned short*)((char*)d_ws + 33554432);  //  4,194,304 B

    float* h_out = (float*)d_out;
    float* c_out = h_out + (size_t)16384 * 512;

    (void)hipFuncSetAttribute(reinterpret_cast<const void*>(lstm_gemm8),
                              hipFuncAttributeMaxDynamicSharedMemorySize, 73728);

    conv_a_kernel<<<8192, 256, 0, stream>>>(x, h, Apre);
    conv_w_kernel<<<1024, 256, 0, stream>>>(W_i, W_f, W_o, W_c, Bpre);
    lstm_gemm8<<<1024, 512, 73728, stream>>>((const char*)Apre, (const char*)Bpre,
                                             c, b_i, b_f, b_o, b_c, h_out, c_out);
}